// Round 10
// baseline (172.658 us; speedup 1.0000x reference)
//
#include <hip/hip_runtime.h>
#include <cstdint>

typedef unsigned short ushort_t;

#define M_ROWS 4096
#define N_COLS 3072
#define K_DIM  1024
#define S_LEN  2048
#define NHEADS 16
#define HDIM   64
#define QSCALE 0.1803368801111204f  /* (1/sqrt(64)) * log2(e) */

typedef __bf16 bf16_t;
typedef bf16_t  bf16x8  __attribute__((ext_vector_type(8)));
typedef short   shortx4 __attribute__((ext_vector_type(4)));
typedef float   floatx4 __attribute__((ext_vector_type(4)));
typedef ushort_t ushortx4 __attribute__((ext_vector_type(4)));

union U32x2S4 { unsigned u[2]; shortx4 s; };

__device__ __forceinline__ unsigned short f2bf(float f) {
  unsigned u = __float_as_uint(f);
  u += 0x7FFFu + ((u >> 16) & 1u);
  return (unsigned short)(u >> 16);
}

// pack two fp32 -> two bf16 in one u32: low=a, high=b (fallback: round-half-up)
__device__ __forceinline__ unsigned pkbf(float a, float b) {
  unsigned ua = __float_as_uint(a) + 0x8000u;
  unsigned ub = __float_as_uint(b) + 0x8000u;
  return __builtin_amdgcn_perm(ub, ua, 0x07060302u);
}

// packed bf16 convert: single v_cvt_pk_bf16_f32 on gfx950 if available
__device__ __forceinline__ unsigned cvtpk(float a, float b) {
#if __has_builtin(__builtin_amdgcn_cvt_pk_bf16_f32)
  auto t = __builtin_amdgcn_cvt_pk_bf16_f32(a, b);
  unsigned r;
  __builtin_memcpy(&r, &t, 4);
  return r;
#else
  return pkbf(a, b);
#endif
}

__device__ __forceinline__ float fexp2(float x) {
#if __has_builtin(__builtin_amdgcn_exp2f)
  return __builtin_amdgcn_exp2f(x);
#else
  float r; asm volatile("v_exp_f32 %0, %1\n\ts_nop 1" : "=v"(r) : "v"(x)); return r;
#endif
}

__device__ __forceinline__ void gload_lds16(const void* g, void* l) {
  __builtin_amdgcn_global_load_lds(
      (const __attribute__((address_space(1))) unsigned int*)g,
      (__attribute__((address_space(3))) unsigned int*)l,
      16, 0, 0);
}

/* ------------------------ fp32 -> bf16 convert (v2: 32B/thread) ---------- */
__global__ __launch_bounds__(256) void cvt_bf16_kernel(
    const float* __restrict__ x, const float* __restrict__ w,
    ushort_t* __restrict__ Xb, ushort_t* __restrict__ Wb) {
  const int NX8 = (M_ROWS * K_DIM) / 8;
  int i = blockIdx.x * 256 + threadIdx.x;
  const float4* src;
  ushort_t* dst;
  int idx;
  if (i < NX8) { src = (const float4*)x; dst = Xb; idx = i; }
  else         { src = (const float4*)w; dst = Wb; idx = i - NX8; }
  float4 a = src[2 * idx];
  float4 b = src[2 * idx + 1];
  uint4 o;
  o.x = cvtpk(a.x, a.y);
  o.y = cvtpk(a.z, a.w);
  o.z = cvtpk(b.x, b.y);
  o.w = cvtpk(b.z, b.w);
  *(uint4*)(dst + 8 * (size_t)idx) = o;
}

/* ------------------------ QKV GEMM (r3 version — empirically best) --------
   m97 structure + LDS XOR chunk swizzle (chunk' = chunk ^ (row&7)),
   conflict-free (verified r3: SQ_LDS_BANK_CONFLICT -> 0). */
__global__ __launch_bounds__(256) void qkv_gemm_kernel(
    const ushort_t* __restrict__ Xb, const ushort_t* __restrict__ Wb,
    const float* __restrict__ bias,
    ushort_t* __restrict__ Qb, ushort_t* __restrict__ Kb, ushort_t* __restrict__ Vb) {
  __shared__ ushort_t As[128 * 64];
  __shared__ ushort_t Bs[128 * 64];
  const int tid = threadIdx.x;
  const int l = tid & 63, w = tid >> 6;
  const int quad = l >> 4, lj = l & 15;
  const int m0 = blockIdx.y * 128, n0 = blockIdx.x * 128;
  const int wm = (w & 1) * 64, wn = (w >> 1) * 64;

  floatx4 acc[4][4] = {};

  const int srow = w * 32 + (l >> 3);
  const int scol = ((l & 7) ^ (l >> 3)) * 8; /* swizzled source chunk */
  const ushort_t* gA = Xb + (size_t)(m0 + srow) * K_DIM + scol;
  const ushort_t* gB = Wb + (size_t)(n0 + srow) * K_DIM + scol;
  ushort_t* lA = As + (w * 32) * 64;
  ushort_t* lB = Bs + (w * 32) * 64;

  const int swr = lj & 7;

  for (int k0 = 0; k0 < K_DIM; k0 += 64) {
    __syncthreads();
#pragma unroll
    for (int c = 0; c < 4; ++c) {
      gload_lds16(gA + (size_t)(c * 8) * K_DIM + k0, lA + c * 8 * 64);
      gload_lds16(gB + (size_t)(c * 8) * K_DIM + k0, lB + c * 8 * 64);
    }
    __syncthreads();
#pragma unroll
    for (int kk = 0; kk < 2; ++kk) {
      const int ch = ((kk * 4 + quad) ^ swr) * 8;
      bf16x8 aF[4], bF[4];
#pragma unroll
      for (int i = 0; i < 4; ++i)
        aF[i] = *(const bf16x8*)(As + (wm + i * 16 + lj) * 64 + ch);
#pragma unroll
      for (int j = 0; j < 4; ++j)
        bF[j] = *(const bf16x8*)(Bs + (wn + j * 16 + lj) * 64 + ch);
#pragma unroll
      for (int i = 0; i < 4; ++i)
#pragma unroll
        for (int j = 0; j < 4; ++j)
          acc[i][j] = __builtin_amdgcn_mfma_f32_16x16x32_bf16(aF[i], bF[j], acc[i][j], 0, 0, 0);
    }
  }

  /* epilogue: n = h*192 + r; r<64 -> Q, r<128 -> K, else V */
#pragma unroll
  for (int j = 0; j < 4; ++j) {
    const int n = n0 + wn + j * 16 + lj;
    const int h = n / 192;
    const int r = n - h * 192;
    const int seg = r >> 6;
    const int d = r & 63;
    const float bv = bias[n];
    ushort_t* dst = (seg == 0) ? Qb : (seg == 1) ? Kb : Vb;
    const float scl = (seg == 0) ? QSCALE : 1.0f;
    const size_t base = (size_t)h * S_LEN * HDIM + d;
#pragma unroll
    for (int i = 0; i < 4; ++i) {
#pragma unroll
      for (int rg = 0; rg < 4; ++rg) {
        const int m = m0 + wm + i * 16 + quad * 4 + rg;
        const int bi = m >> 11;
        const int si = m & 2047;
        dst[base + ((size_t)bi * NHEADS * S_LEN + si) * HDIM] =
            f2bf((acc[i][j][rg] + bv) * scl);
      }
    }
  }
}

/* ------------------------ flash attention (v7: double-buffered) -----------
   Topology = v4.1 EXACT (512 thr x 8 waves, 128-key tiles, grid 512 —
   verified local optimum; r5/r8/r9 repartitions all regressed).
   CHANGE: double-buffered LDS, ONE barrier/iter (17 vs 32). Tile kb+1's
   global loads issue at the TOP of iter kb (gload_lds K -> Ks[nxt], V ->
   VGPRs), so the compiler's vmcnt(0)-before-barrier drains loads that have
   had the whole compute phase in flight (~zero residual latency), unlike
   v4.1 where loads issue right before the barrier (full-latency drain).
   LDS 2x33.5 = 67 KB; 2 blocks/CU (grid-limited) -> occupancy unchanged. */
__global__ __launch_bounds__(512, 4) void attn_kernel(
    const ushort_t* __restrict__ Qb, const ushort_t* __restrict__ Kb,
    const ushort_t* __restrict__ Vb, float* __restrict__ out) {
  __shared__ ushort_t Ks[2][128 * 64];
  __shared__ ushort_t Vs[2][64 * 140];
  const int tid = threadIdx.x;
  const int l = tid & 63, w = tid >> 6;
  const int quad = l >> 4, lj = l & 15;
  const int bh = blockIdx.x >> 4;
  const int qt = blockIdx.x & 15;
  const int q0 = qt * 128 + w * 16;
  const size_t headoff = (size_t)bh * S_LEN * HDIM;

  /* Q fragments: B-operand, n=q=lj, k = kk*32 + quad*8 + j */
  bf16x8 qF[2];
#pragma unroll
  for (int kk = 0; kk < 2; ++kk)
    qF[kk] = *(const bf16x8*)(Qb + headoff + (size_t)(q0 + lj) * HDIM +
                              kk * 32 + quad * 8);

  floatx4 accO[4] = {};
  float l_runA = 0.f, l_runB = 0.f;

  /* K staging with swizzled source chunk; LDS dest stays lane-contiguous */
  const int kr = tid >> 3;
  const int kc = ((tid & 7) ^ (kr & 7)) * 8;
  const ushort_t* gK = Kb + headoff + (size_t)kr * HDIM + kc;

  /* V staging: thread covers (key pair 2sp..2sp+1) x (d quad 4dq..4dq+3) */
  const int dq = tid & 15;
  const int spw = tid >> 4; /* 0..31 */
  const ushort_t* gV = Vb + headoff + dq * 4;
  const int swz = (dq >> 2) << 1; /* V write swizzle, u32-column units */

  const int swk = lj & 7;

  /* prologue: stage tile 0 into buffer 0 */
  {
#pragma unroll
    for (int c = 0; c < 2; ++c)
      gload_lds16(gK + (size_t)(c * 64) * HDIM, &Ks[0][tid * 8 + c * 64 * 64]);
    unsigned* Vn = (unsigned*)Vs[0];
#pragma unroll
    for (int R = 0; R < 2; ++R) {
      const int sp = R * 32 + spw;
      const ushort_t* g = gV + (size_t)(2 * sp) * HDIM;
      const uint2 v0 = *(const uint2*)g;
      const uint2 v1 = *(const uint2*)(g + HDIM);
      const int sp2 = sp ^ swz;
      Vn[(4 * dq + 0) * 70 + sp2] = __builtin_amdgcn_perm(v1.x, v0.x, 0x05040100u);
      Vn[(4 * dq + 1) * 70 + sp2] = __builtin_amdgcn_perm(v1.x, v0.x, 0x07060302u);
      Vn[(4 * dq + 2) * 70 + sp2] = __builtin_amdgcn_perm(v1.y, v0.y, 0x05040100u);
      Vn[(4 * dq + 3) * 70 + sp2] = __builtin_amdgcn_perm(v1.y, v0.y, 0x07060302u);
    }
  }
  __syncthreads();

#pragma unroll 2
  for (int kb = 0; kb < 16; ++kb) {
    const int cur = kb & 1;
    const int nxt = cur ^ 1;

    /* prefetch tile kb+1: K direct-to-LDS, V into registers */
    uint2 pv0[2], pv1[2];
    if (kb < 15) {
      const int kv1 = (kb + 1) * 128;
#pragma unroll
      for (int c = 0; c < 2; ++c)
        gload_lds16(gK + (size_t)(kv1 + c * 64) * HDIM,
                    &Ks[nxt][tid * 8 + c * 64 * 64]);
#pragma unroll
      for (int R = 0; R < 2; ++R) {
        const int sp = R * 32 + spw;
        const ushort_t* g = gV + (size_t)(kv1 + 2 * sp) * HDIM;
        pv0[R] = *(const uint2*)g;
        pv1[R] = *(const uint2*)(g + HDIM);
      }
    }

    /* S^T = K * Q^T : accST[c], key = c*16 + quad*4 + rg, q = lj */
    floatx4 accST[8];
#pragma unroll
    for (int c = 0; c < 8; ++c) {
      const ushort_t* krow = &Ks[cur][(c * 16 + lj) * 64];
      bf16x8 kF0 = *(const bf16x8*)(krow + ((quad ^ swk) * 8));
      bf16x8 kF1 = *(const bf16x8*)(krow + (((quad ^ swk) ^ 4) * 8));
      floatx4 z = {0.f, 0.f, 0.f, 0.f};
      z = __builtin_amdgcn_mfma_f32_16x16x32_bf16(kF0, qF[0], z, 0, 0, 0);
      accST[c] = __builtin_amdgcn_mfma_f32_16x16x32_bf16(kF1, qF[1], z, 0, 0, 0);
    }

    /* no-max softmax: p = exp2(s) (scores pre-scaled by log2(e)/8 via Q) */
    shortx4 aP[8];
    float lsA = 0.f, lsB = 0.f;
#pragma unroll
    for (int c = 0; c < 8; ++c) {
      float p0 = fexp2(accST[c][0]);
      float p1 = fexp2(accST[c][1]);
      float p2 = fexp2(accST[c][2]);
      float p3 = fexp2(accST[c][3]);
      lsA += p0 + p1;
      lsB += p2 + p3;
      U32x2S4 t;
      t.u[0] = cvtpk(p0, p1);
      t.u[1] = cvtpk(p2, p3);
      aP[c] = t.s;
    }
    l_runA += lsA;
    l_runB += lsB;

    /* O += P * V via 16x16x16 bf16; B-frag read applies V swizzle via quad^dt */
#pragma unroll
    for (int dt = 0; dt < 4; ++dt) {
      const ushort_t* vp = &Vs[cur][(dt * 16 + lj) * 140 + (quad ^ dt) * 4];
#pragma unroll
      for (int c = 0; c < 8; ++c) {
        shortx4 vF = *(const shortx4*)(vp + c * 16);
        accO[dt] = __builtin_amdgcn_mfma_f32_16x16x16bf16_1k(aP[c], vF, accO[dt], 0, 0, 0);
      }
    }

    /* complete V prefetch: perm + LDS write into buf[nxt] */
    if (kb < 15) {
      unsigned* Vn = (unsigned*)Vs[nxt];
#pragma unroll
      for (int R = 0; R < 2; ++R) {
        const int sp = R * 32 + spw;
        const int sp2 = sp ^ swz;
        Vn[(4 * dq + 0) * 70 + sp2] = __builtin_amdgcn_perm(pv1[R].x, pv0[R].x, 0x05040100u);
        Vn[(4 * dq + 1) * 70 + sp2] = __builtin_amdgcn_perm(pv1[R].x, pv0[R].x, 0x07060302u);
        Vn[(4 * dq + 2) * 70 + sp2] = __builtin_amdgcn_perm(pv1[R].y, pv0[R].y, 0x05040100u);
        Vn[(4 * dq + 3) * 70 + sp2] = __builtin_amdgcn_perm(pv1[R].y, pv0[R].y, 0x07060302u);
      }
    }
    __syncthreads();
  }

  /* epilogue: O /= l, store fp32 in [b][h][s][d] flat */
  {
    float ls = l_runA + l_runB;
    ls += __shfl_xor(ls, 16, 64);
    ls += __shfl_xor(ls, 32, 64);
    const float inv = 1.0f / ls;
    const int sbase = (l & 48) | (quad * 4);
    float iv[4];
    iv[0] = __shfl(inv, sbase + 0, 64);
    iv[1] = __shfl(inv, sbase + 1, 64);
    iv[2] = __shfl(inv, sbase + 2, 64);
    iv[3] = __shfl(inv, sbase + 3, 64);
#pragma unroll
    for (int dt = 0; dt < 4; ++dt) {
#pragma unroll
      for (int rg = 0; rg < 4; ++rg) {
        const int q = q0 + quad * 4 + rg;
        out[headoff + (size_t)q * HDIM + dt * 16 + lj] = accO[dt][rg] * iv[rg];
      }
    }
  }
}

extern "C" void kernel_launch(void* const* d_in, const int* in_sizes, int n_in,
                              void* d_out, int out_size, void* d_ws, size_t ws_size,
                              hipStream_t stream) {
  (void)in_sizes; (void)n_in; (void)out_size; (void)ws_size;
  const float* x  = (const float*)d_in[0];
  const float* wq = (const float*)d_in[1];
  const float* bq = (const float*)d_in[2];
  float* out = (float*)d_out;

  char* ws = (char*)d_ws;
  ushort_t* Qb = (ushort_t*)(ws);
  ushort_t* Kb = (ushort_t*)(ws + 8388608);
  ushort_t* Vb = (ushort_t*)(ws + 16777216);
  ushort_t* Xb = (ushort_t*)(ws + 25165824);
  ushort_t* Wb = (ushort_t*)(ws + 33554432);

  cvt_bf16_kernel<<<3584, 256, 0, stream>>>(x, wq, Xb, Wb);
  qkv_gemm_kernel<<<dim3(N_COLS / 128, M_ROWS / 128), 256, 0, stream>>>(Xb, Wb, bq, Qb, Kb, Vb);
  attn_kernel<<<512, 512, 0, stream>>>(Qb, Kb, Vb, out);
}

// Round 11
// 160.122 us; speedup vs baseline: 1.0783x; 1.0783x over previous
//
#include <hip/hip_runtime.h>
#include <cstdint>

typedef unsigned short ushort_t;

#define M_ROWS 4096
#define N_COLS 3072
#define K_DIM  1024
#define S_LEN  2048
#define NHEADS 16
#define HDIM   64
#define QSCALE 0.1803368801111204f  /* (1/sqrt(64)) * log2(e) */

typedef __bf16 bf16_t;
typedef bf16_t  bf16x8  __attribute__((ext_vector_type(8)));
typedef short   shortx4 __attribute__((ext_vector_type(4)));
typedef float   floatx4 __attribute__((ext_vector_type(4)));
typedef ushort_t ushortx4 __attribute__((ext_vector_type(4)));

union U32x2S4 { unsigned u[2]; shortx4 s; };

__device__ __forceinline__ unsigned short f2bf(float f) {
  unsigned u = __float_as_uint(f);
  u += 0x7FFFu + ((u >> 16) & 1u);
  return (unsigned short)(u >> 16);
}

// pack two fp32 -> two bf16 in one u32: low=a, high=b (fallback: round-half-up)
__device__ __forceinline__ unsigned pkbf(float a, float b) {
  unsigned ua = __float_as_uint(a) + 0x8000u;
  unsigned ub = __float_as_uint(b) + 0x8000u;
  return __builtin_amdgcn_perm(ub, ua, 0x07060302u);
}

// packed bf16 convert: single v_cvt_pk_bf16_f32 on gfx950 if available
__device__ __forceinline__ unsigned cvtpk(float a, float b) {
#if __has_builtin(__builtin_amdgcn_cvt_pk_bf16_f32)
  auto t = __builtin_amdgcn_cvt_pk_bf16_f32(a, b);
  unsigned r;
  __builtin_memcpy(&r, &t, 4);
  return r;
#else
  return pkbf(a, b);
#endif
}

__device__ __forceinline__ float fexp2(float x) {
#if __has_builtin(__builtin_amdgcn_exp2f)
  return __builtin_amdgcn_exp2f(x);
#else
  float r; asm volatile("v_exp_f32 %0, %1\n\ts_nop 1" : "=v"(r) : "v"(x)); return r;
#endif
}

__device__ __forceinline__ void gload_lds16(const void* g, void* l) {
  __builtin_amdgcn_global_load_lds(
      (const __attribute__((address_space(1))) unsigned int*)g,
      (__attribute__((address_space(3))) unsigned int*)l,
      16, 0, 0);
}

/* ------------------------ fp32 -> bf16 convert (v2: 32B/thread) ---------- */
__global__ __launch_bounds__(256) void cvt_bf16_kernel(
    const float* __restrict__ x, const float* __restrict__ w,
    ushort_t* __restrict__ Xb, ushort_t* __restrict__ Wb) {
  const int NX8 = (M_ROWS * K_DIM) / 8;
  int i = blockIdx.x * 256 + threadIdx.x;
  const float4* src;
  ushort_t* dst;
  int idx;
  if (i < NX8) { src = (const float4*)x; dst = Xb; idx = i; }
  else         { src = (const float4*)w; dst = Wb; idx = i - NX8; }
  float4 a = src[2 * idx];
  float4 b = src[2 * idx + 1];
  uint4 o;
  o.x = cvtpk(a.x, a.y);
  o.y = cvtpk(a.z, a.w);
  o.z = cvtpk(b.x, b.y);
  o.w = cvtpk(b.z, b.w);
  *(uint4*)(dst + 8 * (size_t)idx) = o;
}

/* ------------------------ QKV GEMM (r3 version — empirically best) --------
   m97 structure + LDS XOR chunk swizzle (chunk' = chunk ^ (row&7)),
   conflict-free (verified r3: SQ_LDS_BANK_CONFLICT -> 0). Scalar-store
   epilogue. DO NOT MODIFY without counters. */
__global__ __launch_bounds__(256) void qkv_gemm_kernel(
    const ushort_t* __restrict__ Xb, const ushort_t* __restrict__ Wb,
    const float* __restrict__ bias,
    ushort_t* __restrict__ Qb, ushort_t* __restrict__ Kb, ushort_t* __restrict__ Vb) {
  __shared__ ushort_t As[128 * 64];
  __shared__ ushort_t Bs[128 * 64];
  const int tid = threadIdx.x;
  const int l = tid & 63, w = tid >> 6;
  const int quad = l >> 4, lj = l & 15;
  const int m0 = blockIdx.y * 128, n0 = blockIdx.x * 128;
  const int wm = (w & 1) * 64, wn = (w >> 1) * 64;

  floatx4 acc[4][4] = {};

  const int srow = w * 32 + (l >> 3);
  const int scol = ((l & 7) ^ (l >> 3)) * 8; /* swizzled source chunk */
  const ushort_t* gA = Xb + (size_t)(m0 + srow) * K_DIM + scol;
  const ushort_t* gB = Wb + (size_t)(n0 + srow) * K_DIM + scol;
  ushort_t* lA = As + (w * 32) * 64;
  ushort_t* lB = Bs + (w * 32) * 64;

  const int swr = lj & 7;

  for (int k0 = 0; k0 < K_DIM; k0 += 64) {
    __syncthreads();
#pragma unroll
    for (int c = 0; c < 4; ++c) {
      gload_lds16(gA + (size_t)(c * 8) * K_DIM + k0, lA + c * 8 * 64);
      gload_lds16(gB + (size_t)(c * 8) * K_DIM + k0, lB + c * 8 * 64);
    }
    __syncthreads();
#pragma unroll
    for (int kk = 0; kk < 2; ++kk) {
      const int ch = ((kk * 4 + quad) ^ swr) * 8;
      bf16x8 aF[4], bF[4];
#pragma unroll
      for (int i = 0; i < 4; ++i)
        aF[i] = *(const bf16x8*)(As + (wm + i * 16 + lj) * 64 + ch);
#pragma unroll
      for (int j = 0; j < 4; ++j)
        bF[j] = *(const bf16x8*)(Bs + (wn + j * 16 + lj) * 64 + ch);
#pragma unroll
      for (int i = 0; i < 4; ++i)
#pragma unroll
        for (int j = 0; j < 4; ++j)
          acc[i][j] = __builtin_amdgcn_mfma_f32_16x16x32_bf16(aF[i], bF[j], acc[i][j], 0, 0, 0);
    }
  }

  /* epilogue: n = h*192 + r; r<64 -> Q, r<128 -> K, else V */
#pragma unroll
  for (int j = 0; j < 4; ++j) {
    const int n = n0 + wn + j * 16 + lj;
    const int h = n / 192;
    const int r = n - h * 192;
    const int seg = r >> 6;
    const int d = r & 63;
    const float bv = bias[n];
    ushort_t* dst = (seg == 0) ? Qb : (seg == 1) ? Kb : Vb;
    const float scl = (seg == 0) ? QSCALE : 1.0f;
    const size_t base = (size_t)h * S_LEN * HDIM + d;
#pragma unroll
    for (int i = 0; i < 4; ++i) {
#pragma unroll
      for (int rg = 0; rg < 4; ++rg) {
        const int m = m0 + wm + i * 16 + quad * 4 + rg;
        const int bi = m >> 11;
        const int si = m & 2047;
        dst[base + ((size_t)bi * NHEADS * S_LEN + si) * HDIM] =
            f2bf((acc[i][j][rg] + bv) * scl);
      }
    }
  }
}

/* ------------------------ flash attention (v4.2: XCD swizzle) -------------
   Inner loop + topology = v4.1 EXACT (verified 52us best; r5/r8/r9/r10
   repartition/tile/dbuf variants ALL regressed — do not revisit).
   CHANGE: block index swizzle bh = blk&31, qt = blk>>5. Same-head q-tile
   blocks are spaced 32 apart -> with round-robin blockIdx%8 XCD dispatch
   they all land on XCD bh%8: 4 heads/XCD = 2 MB K/V working set < 4 MB L2.
   Old mapping spread one head's 16 blocks over all XCDs (FETCH 69.7 MB vs
   24 MB ideal). Pure index remap; correctness-neutral. */
__global__ __launch_bounds__(512, 4) void attn_kernel(
    const ushort_t* __restrict__ Qb, const ushort_t* __restrict__ Kb,
    const ushort_t* __restrict__ Vb, float* __restrict__ out) {
  __shared__ ushort_t Ks[128 * 64];
  __shared__ ushort_t Vs[64 * 140];
  const int tid = threadIdx.x;
  const int l = tid & 63, w = tid >> 6;
  const int quad = l >> 4, lj = l & 15;
  const int bh = blockIdx.x & 31;   /* v4.2: swizzled (was blk>>4) */
  const int qt = blockIdx.x >> 5;   /* v4.2: swizzled (was blk&15) */
  const int q0 = qt * 128 + w * 16;
  const size_t headoff = (size_t)bh * S_LEN * HDIM;

  /* Q fragments: B-operand, n=q=lj, k = kk*32 + quad*8 + j */
  bf16x8 qF[2];
#pragma unroll
  for (int kk = 0; kk < 2; ++kk)
    qF[kk] = *(const bf16x8*)(Qb + headoff + (size_t)(q0 + lj) * HDIM +
                              kk * 32 + quad * 8);

  floatx4 accO[4] = {};
  float l_runA = 0.f, l_runB = 0.f;

  /* K staging with swizzled source chunk; LDS dest stays lane-contiguous */
  const int kr = tid >> 3;
  const int kc = ((tid & 7) ^ (kr & 7)) * 8;
  const ushort_t* gK = Kb + headoff + (size_t)kr * HDIM + kc;
  ushort_t* lK = Ks + tid * 8;

  /* V staging: thread covers (key pair 2sp..2sp+1) x (d quad 4dq..4dq+3) */
  const int dq = tid & 15;
  const int spw = tid >> 4; /* 0..31 */
  const ushort_t* gV = Vb + headoff + dq * 4;
  unsigned* Vs32 = (unsigned*)Vs;
  const int swz = (dq >> 2) << 1; /* V write swizzle, u32-column units */

  const int swk = lj & 7;

  for (int kb = 0; kb < 16; ++kb) {
    const int kv0 = kb * 128;
    __syncthreads();
#pragma unroll
    for (int c = 0; c < 2; ++c)
      gload_lds16(gK + (size_t)(kv0 + c * 64) * HDIM, lK + c * 64 * 64);
#pragma unroll
    for (int R = 0; R < 2; ++R) {
      const int sp = R * 32 + spw; /* 0..63 */
      const ushort_t* g = gV + (size_t)(kv0 + 2 * sp) * HDIM;
      const uint2 v0 = *(const uint2*)g;          /* key s   : d..d+3 */
      const uint2 v1 = *(const uint2*)(g + HDIM); /* key s+1 : d..d+3 */
      unsigned o0 = __builtin_amdgcn_perm(v1.x, v0.x, 0x05040100u);
      unsigned o1 = __builtin_amdgcn_perm(v1.x, v0.x, 0x07060302u);
      unsigned o2 = __builtin_amdgcn_perm(v1.y, v0.y, 0x05040100u);
      unsigned o3 = __builtin_amdgcn_perm(v1.y, v0.y, 0x07060302u);
      const int sp2 = sp ^ swz;
      Vs32[(4 * dq + 0) * 70 + sp2] = o0;
      Vs32[(4 * dq + 1) * 70 + sp2] = o1;
      Vs32[(4 * dq + 2) * 70 + sp2] = o2;
      Vs32[(4 * dq + 3) * 70 + sp2] = o3;
    }
    __syncthreads();

    /* S^T = K * Q^T : accST[c], key = c*16 + quad*4 + rg, q = lj */
    floatx4 accST[8];
#pragma unroll
    for (int c = 0; c < 8; ++c) {
      const ushort_t* krow = Ks + (c * 16 + lj) * 64;
      bf16x8 kF0 = *(const bf16x8*)(krow + ((quad ^ swk) * 8));
      bf16x8 kF1 = *(const bf16x8*)(krow + (((quad ^ swk) ^ 4) * 8));
      floatx4 z = {0.f, 0.f, 0.f, 0.f};
      z = __builtin_amdgcn_mfma_f32_16x16x32_bf16(kF0, qF[0], z, 0, 0, 0);
      accST[c] = __builtin_amdgcn_mfma_f32_16x16x32_bf16(kF1, qF[1], z, 0, 0, 0);
    }

    /* no-max softmax: p = exp2(s) (scores pre-scaled by log2(e)/8 via Q) */
    shortx4 aP[8];
    float lsA = 0.f, lsB = 0.f;
#pragma unroll
    for (int c = 0; c < 8; ++c) {
      float p0 = fexp2(accST[c][0]);
      float p1 = fexp2(accST[c][1]);
      float p2 = fexp2(accST[c][2]);
      float p3 = fexp2(accST[c][3]);
      lsA += p0 + p1;
      lsB += p2 + p3;
      U32x2S4 t;
      t.u[0] = cvtpk(p0, p1);
      t.u[1] = cvtpk(p2, p3);
      aP[c] = t.s;
    }
    l_runA += lsA;
    l_runB += lsB;

    /* O += P * V via 16x16x16 bf16; B-frag read applies V swizzle via quad^dt */
#pragma unroll
    for (int dt = 0; dt < 4; ++dt) {
      const ushort_t* vp = Vs + (dt * 16 + lj) * 140 + (quad ^ dt) * 4;
#pragma unroll
      for (int c = 0; c < 8; ++c) {
        shortx4 vF = *(const shortx4*)(vp + c * 16);
        accO[dt] = __builtin_amdgcn_mfma_f32_16x16x16bf16_1k(aP[c], vF, accO[dt], 0, 0, 0);
      }
    }
  }

  /* epilogue: O /= l, store fp32 in [b][h][s][d] flat */
  {
    float ls = l_runA + l_runB;
    ls += __shfl_xor(ls, 16, 64);
    ls += __shfl_xor(ls, 32, 64);
    const float inv = 1.0f / ls;
    const int sbase = (l & 48) | (quad * 4);
    float iv[4];
    iv[0] = __shfl(inv, sbase + 0, 64);
    iv[1] = __shfl(inv, sbase + 1, 64);
    iv[2] = __shfl(inv, sbase + 2, 64);
    iv[3] = __shfl(inv, sbase + 3, 64);
#pragma unroll
    for (int dt = 0; dt < 4; ++dt) {
#pragma unroll
      for (int rg = 0; rg < 4; ++rg) {
        const int q = q0 + quad * 4 + rg;
        out[headoff + (size_t)q * HDIM + dt * 16 + lj] = accO[dt][rg] * iv[rg];
      }
    }
  }
}

extern "C" void kernel_launch(void* const* d_in, const int* in_sizes, int n_in,
                              void* d_out, int out_size, void* d_ws, size_t ws_size,
                              hipStream_t stream) {
  (void)in_sizes; (void)n_in; (void)out_size; (void)ws_size;
  const float* x  = (const float*)d_in[0];
  const float* wq = (const float*)d_in[1];
  const float* bq = (const float*)d_in[2];
  float* out = (float*)d_out;

  char* ws = (char*)d_ws;
  ushort_t* Qb = (ushort_t*)(ws);
  ushort_t* Kb = (ushort_t*)(ws + 8388608);
  ushort_t* Vb = (ushort_t*)(ws + 16777216);
  ushort_t* Xb = (ushort_t*)(ws + 25165824);
  ushort_t* Wb = (ushort_t*)(ws + 33554432);

  cvt_bf16_kernel<<<3584, 256, 0, stream>>>(x, wq, Xb, Wb);
  qkv_gemm_kernel<<<dim3(N_COLS / 128, M_ROWS / 128), 256, 0, stream>>>(Xb, Wb, bq, Qb, Kb, Vb);
  attn_kernel<<<512, 512, 0, stream>>>(Qb, Kb, Vb, out);
}